// Round 2
// baseline (11792.723 us; speedup 1.0000x reference)
//
#include <hip/hip_runtime.h>
#include <hip/hip_bf16.h>

// Problem constants
#define BB   2
#define SS   2048
#define HH   2048
#define NHH  16
#define QLL  1536
#define KVLL 512
#define NOPE_D 128
#define ROPE_D 64
#define QKH_D  192
#define VD_D   128
#define MROWS  (BB*SS)           // 4096 token rows

__device__ inline float4 load4(const float* p) { return *(const float4*)p; }
__device__ inline void store4(float* p, float4 v) { *(float4*)p = v; }

// ---------------------------------------------------------------------------
// Generic C = A @ B^T + bias.  A: (M,K) lda. B: (N,K) row-major f32 (ldb=K).
// C: (M,N) ldc.  64x64 tile, BK=16, 256 threads, 4x4 microtile.
// All shapes here are multiples of 64 (M=4096; N in {1536,3072,576,2048}) and
// K multiples of 16 -> no bounds checks.
// ---------------------------------------------------------------------------
__launch_bounds__(256)
__global__ void gemm_nt(const float* __restrict__ A, const float* __restrict__ B,
                        const float* __restrict__ bias, float* __restrict__ C,
                        int M, int N, int K, int lda, int ldc)
{
    __shared__ float As[16][68];
    __shared__ float Bs[16][68];
    const int tid = threadIdx.x;
    const int tx = tid & 15, ty = tid >> 4;
    const int n0 = blockIdx.x * 64, m0 = blockIdx.y * 64;
    const int lr = tid >> 2;          // 0..63 tile row
    const int lk = (tid & 3) * 4;     // 0,4,8,12 k offset

    float acc[4][4] = {};

    const float* Ap = A + (size_t)(m0 + lr) * lda + lk;
    const float* Bp = B + (size_t)(n0 + lr) * K + lk;

    for (int k0 = 0; k0 < K; k0 += 16) {
        float4 av = load4(Ap + k0);
        float4 bv = load4(Bp + k0);
        As[lk + 0][lr] = av.x; As[lk + 1][lr] = av.y;
        As[lk + 2][lr] = av.z; As[lk + 3][lr] = av.w;
        Bs[lk + 0][lr] = bv.x; Bs[lk + 1][lr] = bv.y;
        Bs[lk + 2][lr] = bv.z; Bs[lk + 3][lr] = bv.w;
        __syncthreads();
#pragma unroll
        for (int kk = 0; kk < 16; kk++) {
            float4 a = *(const float4*)&As[kk][ty * 4];
            float4 b = *(const float4*)&Bs[kk][tx * 4];
            acc[0][0] += a.x * b.x; acc[0][1] += a.x * b.y; acc[0][2] += a.x * b.z; acc[0][3] += a.x * b.w;
            acc[1][0] += a.y * b.x; acc[1][1] += a.y * b.y; acc[1][2] += a.y * b.z; acc[1][3] += a.y * b.w;
            acc[2][0] += a.z * b.x; acc[2][1] += a.z * b.y; acc[2][2] += a.z * b.z; acc[2][3] += a.z * b.w;
            acc[3][0] += a.w * b.x; acc[3][1] += a.w * b.y; acc[3][2] += a.w * b.z; acc[3][3] += a.w * b.w;
        }
        __syncthreads();
    }

    float4 bb = load4(bias + n0 + tx * 4);
#pragma unroll
    for (int i = 0; i < 4; i++) {
        float4 v = make_float4(acc[i][0] + bb.x, acc[i][1] + bb.y,
                               acc[i][2] + bb.z, acc[i][3] + bb.w);
        store4(&C[(size_t)(m0 + ty * 4 + i) * ldc + n0 + tx * 4], v);
    }
}

// ---------------------------------------------------------------------------
// In-place RMSNorm over `width` leading columns of each row (row stride
// `stride`).  x = w * x * rsqrt(mean(x^2) + eps).  One 256-thread block/row.
// ---------------------------------------------------------------------------
__launch_bounds__(256)
__global__ void rmsnorm_kernel(float* __restrict__ x, const float* __restrict__ w,
                               int width, int stride)
{
    float* xr = x + (size_t)blockIdx.x * stride;
    float ss = 0.f;
    for (int i = threadIdx.x; i < width; i += 256) { float v = xr[i]; ss += v * v; }
    __shared__ float red[256];
    red[threadIdx.x] = ss; __syncthreads();
    for (int o = 128; o > 0; o >>= 1) {
        if (threadIdx.x < o) red[threadIdx.x] += red[threadIdx.x + o];
        __syncthreads();
    }
    float r = rsqrtf(red[0] / (float)width + 1e-6f);
    for (int i = threadIdx.x; i < width; i += 256)
        xr[i] = w[i] * xr[i] * r;
}

__device__ inline float rope_apply(const float* p, int j, int s)
{
    int i = j & 31;
    float freq = powf(10000.f, -(float)i / 32.f);
    float a = (float)s * freq;
    float sn, cs; sincosf(a, &sn, &cs);
    float xj = p[j];
    float other = (j < 32) ? -p[j + 32] : p[j - 32];
    return xj * cs + other * sn;
}

// RoPE in place on kv_full cols [512,576). 4096 blocks x 64 threads.
// Single wave: both loads (p[j], p[j^32]) issue before the store for all
// lanes, so in-place is race-free.
__global__ void rope_k_kernel(float* __restrict__ kvf)
{
    int m = blockIdx.x, s = m & (SS - 1), j = threadIdx.x;
    float* p = kvf + (size_t)m * 576 + 512;
    float v = rope_apply(p, j, s);
    p[j] = v;
}

// RoPE in place on q pe slices: cols h*192+128 .. +191.  grid (4096,4) x 256.
// Each wave owns one head's 64-wide pe slice -> race-free in place.
__global__ void rope_q_kernel(float* __restrict__ q)
{
    int m = blockIdx.x, s = m & (SS - 1);
    int wid = threadIdx.x >> 6, j = threadIdx.x & 63;
    int h = blockIdx.y * 4 + wid;
    float* p = q + (size_t)m * 3072 + h * 192 + 128;
    float v = rope_apply(p, j, s);
    p[j] = v;
}

// ---------------------------------------------------------------------------
// Fused absorbed attention.  One wave per (b,h,s) row:
//   prologue: q_lat[c] = sum_d q_nope[d] * W_UK[h][d][c]      (c=512, in regs)
//   stream t=0..s: score = (q_lat.kv[t] + q_pe.k_pe[t])/sqrt(192),
//                  online softmax, acc += p*kv[t]
//   epilogue: o[h*128+d] = sum_c (acc[c]/l) * W_UV[h][d][c]
// Block = 4 waves = 4 consecutive s for the same (b,h)  (L1 kv reuse).
// ---------------------------------------------------------------------------
__launch_bounds__(256)
__global__ void attn_kernel(const float* __restrict__ q, const float* __restrict__ kvf,
                            const float* __restrict__ wkv_b,
                            const int* __restrict__ mask, float* __restrict__ o_heads)
{
    __shared__ float accsh[4][516];
    const int wid = threadIdx.x >> 6, lane = threadIdx.x & 63;
    const int sg = blockIdx.x & (SS / 4 - 1);
    const int h  = (blockIdx.x >> 9) & (NHH - 1);
    const int b  = blockIdx.x >> 13;
    const int s  = sg * 4 + wid;
    const int m  = b * SS + s;

    const float* qrow = q + (size_t)m * 3072 + h * QKH_D;

    // q_lat GEMV: lane owns cols {4l..4l+3} and {256+4l..+3}
    const float* WUK = wkv_b + (size_t)(h * 256) * 512;
    float qa0 = 0, qa1 = 0, qa2 = 0, qa3 = 0, qb0 = 0, qb1 = 0, qb2 = 0, qb3 = 0;
    for (int d = 0; d < 128; d++) {
        float qd = qrow[d];
        float4 wa = load4(WUK + (size_t)d * 512 + 4 * lane);
        float4 wb = load4(WUK + (size_t)d * 512 + 256 + 4 * lane);
        qa0 += qd * wa.x; qa1 += qd * wa.y; qa2 += qd * wa.z; qa3 += qd * wa.w;
        qb0 += qd * wb.x; qb1 += qd * wb.y; qb2 += qd * wb.z; qb3 += qd * wb.w;
    }
    float qpe = qrow[NOPE_D + lane];

    const float* kvb = kvf + (size_t)b * SS * 576;
    const int* mrow = mask + b * SS;

    const float scale = 0.07216878364870323f;   // 1/sqrt(192)
    float mrun = -3.0e38f, l = 0.f;
    float a0 = 0, a1 = 0, a2 = 0, a3 = 0, b0 = 0, b1 = 0, b2 = 0, b3 = 0;

    for (int t = 0; t <= s; t++) {
        if (mrow[t] == 0) continue;
        const float* kr = kvb + (size_t)t * 576;
        float4 ka = *(const float4*)(kr + 4 * lane);
        float4 kb = *(const float4*)(kr + 256 + 4 * lane);
        float kp = kr[512 + lane];
        float part = qa0 * ka.x + qa1 * ka.y + qa2 * ka.z + qa3 * ka.w
                   + qb0 * kb.x + qb1 * kb.y + qb2 * kb.z + qb3 * kb.w
                   + qpe * kp;
#pragma unroll
        for (int o = 32; o > 0; o >>= 1) part += __shfl_xor(part, o);
        float sc = part * scale;
        float mn = fmaxf(mrun, sc);
        float alpha = __expf(mrun - mn);
        float pw = __expf(sc - mn);
        l = l * alpha + pw;
        a0 = a0 * alpha + pw * ka.x; a1 = a1 * alpha + pw * ka.y;
        a2 = a2 * alpha + pw * ka.z; a3 = a3 * alpha + pw * ka.w;
        b0 = b0 * alpha + pw * kb.x; b1 = b1 * alpha + pw * kb.y;
        b2 = b2 * alpha + pw * kb.z; b3 = b3 * alpha + pw * kb.w;
        mrun = mn;
    }

    float invl = (l > 0.f) ? 1.f / l : 0.f;
    store4(&accsh[wid][4 * lane],        make_float4(a0 * invl, a1 * invl, a2 * invl, a3 * invl));
    store4(&accsh[wid][256 + 4 * lane],  make_float4(b0 * invl, b1 * invl, b2 * invl, b3 * invl));
    // same-wave LDS producer/consumer: in-order DS pipe, no barrier needed

    const float* WUV = wkv_b + (size_t)(h * 256 + 128) * 512;
    float o0 = 0.f, o1 = 0.f;
    for (int c = 0; c < 512; c += 4) {
        float4 a = *(const float4*)&accsh[wid][c];
        float4 w0 = load4(WUV + (size_t)lane * 512 + c);
        float4 w1 = load4(WUV + (size_t)(lane + 64) * 512 + c);
        o0 += a.x * w0.x + a.y * w0.y + a.z * w0.z + a.w * w0.w;
        o1 += a.x * w1.x + a.y * w1.y + a.z * w1.z + a.w * w1.w;
    }
    float* orow = o_heads + (size_t)m * 2048 + h * 128;
    orow[lane] = o0;
    orow[lane + 64] = o1;
}

extern "C" void kernel_launch(void* const* d_in, const int* in_sizes, int n_in,
                              void* d_out, int out_size, void* d_ws, size_t ws_size,
                              hipStream_t stream)
{
    const float* x        = (const float*)d_in[0];
    const int*   mask     = (const int*)d_in[1];
    const float* wq_a_w   = (const float*)d_in[2];
    const float* wq_a_b   = (const float*)d_in[3];
    const float* q_norm_w = (const float*)d_in[4];
    const float* wq_b_w   = (const float*)d_in[5];
    const float* wq_b_b   = (const float*)d_in[6];
    const float* wkv_a_w  = (const float*)d_in[7];
    const float* wkv_a_b  = (const float*)d_in[8];
    const float* kv_norm_w= (const float*)d_in[9];
    const float* wkv_b_w  = (const float*)d_in[10];
    const float* wo_w     = (const float*)d_in[11];
    const float* wo_b     = (const float*)d_in[12];
    float* out = (float*)d_out;

    // Workspace layout (q_a aliases o_heads region; q_a dead before attn):
    float* ws      = (float*)d_ws;
    float* qbuf    = ws;                                   // 4096*3072
    float* kvf     = qbuf + (size_t)MROWS * (NHH * QKH_D); // 4096*576
    float* shared_r= kvf  + (size_t)MROWS * 576;           // max(q_a, o_heads)
    float* q_a     = shared_r;                             // 4096*1536
    float* o_heads = shared_r;                             // 4096*2048

    // q_a = x @ wq_a^T + b
    gemm_nt<<<dim3(QLL / 64, MROWS / 64), 256, 0, stream>>>(
        x, wq_a_w, wq_a_b, q_a, MROWS, QLL, HH, HH, QLL);
    // rms_norm(q_a)
    rmsnorm_kernel<<<MROWS, 256, 0, stream>>>(q_a, q_norm_w, QLL, QLL);
    // q = q_a @ wq_b^T + b
    gemm_nt<<<dim3(NHH * QKH_D / 64, MROWS / 64), 256, 0, stream>>>(
        q_a, wq_b_w, wq_b_b, qbuf, MROWS, NHH * QKH_D, QLL, QLL, NHH * QKH_D);
    // kv_full = x @ wkv_a^T + b
    gemm_nt<<<dim3((KVLL + ROPE_D) / 64, MROWS / 64), 256, 0, stream>>>(
        x, wkv_a_w, wkv_a_b, kvf, MROWS, KVLL + ROPE_D, HH, HH, KVLL + ROPE_D);
    // rms_norm on kv latent part (in place, stride 576)
    rmsnorm_kernel<<<MROWS, 256, 0, stream>>>(kvf, kv_norm_w, KVLL, 576);
    // rope on k_pe (in place)
    rope_k_kernel<<<MROWS, 64, 0, stream>>>(kvf);
    // rope on q pe slices (in place)
    rope_q_kernel<<<dim3(MROWS, 4), 256, 0, stream>>>(qbuf);
    // fused absorbed attention -> o_heads
    attn_kernel<<<BB * NHH * (SS / 4), 256, 0, stream>>>(qbuf, kvf, wkv_b_w, mask, o_heads);
    // out = o_heads @ wo^T + b
    gemm_nt<<<dim3(HH / 64, MROWS / 64), 256, 0, stream>>>(
        o_heads, wo_w, wo_b, out, MROWS, HH, NHH * VD_D, NHH * VD_D, HH);
}

// Round 3
// 3869.011 us; speedup vs baseline: 3.0480x; 3.0480x over previous
//
#include <hip/hip_runtime.h>
#include <hip/hip_bf16.h>

#define BB   2
#define SS   2048
#define HH   2048
#define NHH  16
#define QLL  1536
#define KVLL 512
#define NOPE_D 128
#define ROPE_D 64
#define QKH_D  192
#define VD_D   128
#define MROWS  (BB*SS)           // 4096 token rows

typedef __attribute__((ext_vector_type(8))) short bf16x8;   // 8 bf16 (4 VGPRs)
typedef __attribute__((ext_vector_type(4))) float f32x4;    // MFMA accumulator

__device__ inline float bf2f(unsigned short u) {
    union { float f; unsigned int i; } v; v.i = ((unsigned int)u) << 16; return v.f;
}
__device__ inline unsigned short f2bf(float f) {
    union { float f; unsigned int u; } v; v.f = f;
    unsigned int r = v.u + 0x7fffu + ((v.u >> 16) & 1u);
    return (unsigned short)(r >> 16);
}

__device__ inline float4 load4(const float* p) { return *(const float4*)p; }
__device__ inline float4 load4(const ushort* p) {
    ushort4 u = *(const ushort4*)p;
    return make_float4(bf2f(u.x), bf2f(u.y), bf2f(u.z), bf2f(u.w));
}
__device__ inline void store4(float* p, float4 v) { *(float4*)p = v; }
__device__ inline void store4(ushort* p, float4 v) {
    ushort4 u; u.x = f2bf(v.x); u.y = f2bf(v.y); u.z = f2bf(v.z); u.w = f2bf(v.w);
    *(ushort4*)p = u;
}

// ---------------------------------------------------------------------------
// C = A @ B^T + bias.  A: (M,K) f32 or bf16. B: (N,K) f32 weights. C f32/bf16.
// 64x64 tile, BK=16, 256 threads, 4x4 microtile. All dims multiples of 64/16.
// ---------------------------------------------------------------------------
template<typename TA, typename TC>
__launch_bounds__(256)
__global__ void gemm_nt(const TA* __restrict__ A, const float* __restrict__ B,
                        const float* __restrict__ bias, TC* __restrict__ C,
                        int M, int N, int K, int lda, int ldc)
{
    __shared__ float As[16][68];
    __shared__ float Bs[16][68];
    const int tid = threadIdx.x;
    const int tx = tid & 15, ty = tid >> 4;
    const int n0 = blockIdx.x * 64, m0 = blockIdx.y * 64;
    const int lr = tid >> 2;          // 0..63 tile row
    const int lk = (tid & 3) * 4;     // 0,4,8,12 k offset

    float acc[4][4] = {};

    const TA* Ap = A + (size_t)(m0 + lr) * lda + lk;
    const float* Bp = B + (size_t)(n0 + lr) * K + lk;

    for (int k0 = 0; k0 < K; k0 += 16) {
        float4 av = load4(Ap + k0);
        float4 bv = load4(Bp + k0);
        As[lk + 0][lr] = av.x; As[lk + 1][lr] = av.y;
        As[lk + 2][lr] = av.z; As[lk + 3][lr] = av.w;
        Bs[lk + 0][lr] = bv.x; Bs[lk + 1][lr] = bv.y;
        Bs[lk + 2][lr] = bv.z; Bs[lk + 3][lr] = bv.w;
        __syncthreads();
#pragma unroll
        for (int kk = 0; kk < 16; kk++) {
            float4 a = *(const float4*)&As[kk][ty * 4];
            float4 b = *(const float4*)&Bs[kk][tx * 4];
            acc[0][0] += a.x * b.x; acc[0][1] += a.x * b.y; acc[0][2] += a.x * b.z; acc[0][3] += a.x * b.w;
            acc[1][0] += a.y * b.x; acc[1][1] += a.y * b.y; acc[1][2] += a.y * b.z; acc[1][3] += a.y * b.w;
            acc[2][0] += a.z * b.x; acc[2][1] += a.z * b.y; acc[2][2] += a.z * b.z; acc[2][3] += a.z * b.w;
            acc[3][0] += a.w * b.x; acc[3][1] += a.w * b.y; acc[3][2] += a.w * b.z; acc[3][3] += a.w * b.w;
        }
        __syncthreads();
    }

    float4 bb = load4(bias + n0 + tx * 4);
#pragma unroll
    for (int i = 0; i < 4; i++) {
        float4 v = make_float4(acc[i][0] + bb.x, acc[i][1] + bb.y,
                               acc[i][2] + bb.z, acc[i][3] + bb.w);
        store4(&C[(size_t)(m0 + ty * 4 + i) * ldc + n0 + tx * 4], v);
    }
}

// ---------------------------------------------------------------------------
// In-place f32 RMSNorm (q_a).
// ---------------------------------------------------------------------------
__launch_bounds__(256)
__global__ void rmsnorm_kernel(float* __restrict__ x, const float* __restrict__ w,
                               int width, int stride)
{
    float* xr = x + (size_t)blockIdx.x * stride;
    float ss = 0.f;
    for (int i = threadIdx.x; i < width; i += 256) { float v = xr[i]; ss += v * v; }
    __shared__ float red[256];
    red[threadIdx.x] = ss; __syncthreads();
    for (int o = 128; o > 0; o >>= 1) {
        if (threadIdx.x < o) red[threadIdx.x] += red[threadIdx.x + o];
        __syncthreads();
    }
    float r = rsqrtf(red[0] / (float)width + 1e-6f);
    for (int i = threadIdx.x; i < width; i += 256)
        xr[i] = w[i] * xr[i] * r;
}

__device__ inline float rope_val(float xj, float xo, int j, int s)
{
    int i = j & 31;
    float freq = powf(10000.f, -(float)i / 32.f);
    float a = (float)s * freq;
    float sn, cs; sincosf(a, &sn, &cs);
    float other = (j < 32) ? -xo : xo;
    return xj * cs + other * sn;
}

// ---------------------------------------------------------------------------
// kv finalize: rms_norm on latent 512, rope on pe 64; write kv_bf row-major
// bf16 and kvT[b][c][s] transposed latent bf16.  grid 4096 x 256.
// ---------------------------------------------------------------------------
__launch_bounds__(256)
__global__ void finalize_kv(const float* __restrict__ kvf, const float* __restrict__ w,
                            ushort* __restrict__ kvbf, ushort* __restrict__ kvT)
{
    int m = blockIdx.x; int b = m >> 11, s = m & (SS - 1);
    const float* xr = kvf + (size_t)m * 576;
    float ss = 0.f;
    for (int i = threadIdx.x; i < 512; i += 256) { float v = xr[i]; ss += v * v; }
    __shared__ float red[256];
    red[threadIdx.x] = ss; __syncthreads();
    for (int o = 128; o > 0; o >>= 1) {
        if (threadIdx.x < o) red[threadIdx.x] += red[threadIdx.x + o];
        __syncthreads();
    }
    float r = rsqrtf(red[0] / 512.f + 1e-6f);
    for (int i = threadIdx.x; i < 512; i += 256) {
        ushort u = f2bf(w[i] * xr[i] * r);
        kvbf[(size_t)m * 576 + i] = u;
        kvT[((size_t)b * 512 + i) * SS + s] = u;
    }
    if (threadIdx.x < 64) {
        int j = threadIdx.x;
        float xj = xr[512 + j];
        float xo = xr[512 + (j ^ 32)];
        kvbf[(size_t)m * 576 + 512 + j] = f2bf(rope_val(xj, xo, j, s));
    }
}

// ---------------------------------------------------------------------------
// RoPE q_pe: read qbuf bf16, write qprime[...][512..575].  grid (4096,4) x 256.
// ---------------------------------------------------------------------------
__global__ void rope_q_kernel(const ushort* __restrict__ qbuf, ushort* __restrict__ qprime)
{
    int m = blockIdx.x, s = m & (SS - 1), b = m >> 11;
    int w = threadIdx.x >> 6, j = threadIdx.x & 63;
    int h = blockIdx.y * 4 + w;
    const ushort* p = qbuf + (size_t)m * 3072 + h * QKH_D + NOPE_D;
    float xj = bf2f(p[j]);
    float xo = bf2f(p[j ^ 32]);
    qprime[((size_t)(b * NHH + h) * SS + s) * 576 + 512 + j] = f2bf(rope_val(xj, xo, j, s));
}

// ---------------------------------------------------------------------------
// q_lat: per (b,h): C(2048x512) = q_nope(2048x128 bf16) @ W_UK[h](128x512 f32),
// written bf16 into qprime[...][0..511].  grid (8, 32, 32) x 256.
// ---------------------------------------------------------------------------
__launch_bounds__(256)
__global__ void qlat_gemm(const ushort* __restrict__ qbuf, const float* __restrict__ wkv_b,
                          ushort* __restrict__ qprime)
{
    __shared__ float As[16][68];
    __shared__ float Bs[16][68];
    const int tid = threadIdx.x;
    const int tx = tid & 15, ty = tid >> 4;
    const int n0 = blockIdx.x * 64, m0 = blockIdx.y * 64;
    const int z = blockIdx.z; const int b = z >> 4, h = z & 15;
    const int lr = tid >> 2, lk = (tid & 3) * 4;

    float acc[4][4] = {};
    const ushort* Ap = qbuf + ((size_t)(b * SS) + m0 + lr) * 3072 + h * QKH_D + lk;
    const float* W = wkv_b + (size_t)(h * 256) * 512;
    const int bk = tid >> 4, bn = (tid & 15) * 4;

    for (int k0 = 0; k0 < 128; k0 += 16) {
        float4 av = load4(Ap + k0);
        As[lk + 0][lr] = av.x; As[lk + 1][lr] = av.y;
        As[lk + 2][lr] = av.z; As[lk + 3][lr] = av.w;
        float4 bv = load4(W + (size_t)(k0 + bk) * 512 + n0 + bn);
        Bs[bk][bn + 0] = bv.x; Bs[bk][bn + 1] = bv.y;
        Bs[bk][bn + 2] = bv.z; Bs[bk][bn + 3] = bv.w;
        __syncthreads();
#pragma unroll
        for (int kk = 0; kk < 16; kk++) {
            float4 a = *(const float4*)&As[kk][ty * 4];
            float4 b4 = *(const float4*)&Bs[kk][tx * 4];
            acc[0][0] += a.x * b4.x; acc[0][1] += a.x * b4.y; acc[0][2] += a.x * b4.z; acc[0][3] += a.x * b4.w;
            acc[1][0] += a.y * b4.x; acc[1][1] += a.y * b4.y; acc[1][2] += a.y * b4.z; acc[1][3] += a.y * b4.w;
            acc[2][0] += a.z * b4.x; acc[2][1] += a.z * b4.y; acc[2][2] += a.z * b4.z; acc[2][3] += a.z * b4.w;
            acc[3][0] += a.w * b4.x; acc[3][1] += a.w * b4.y; acc[3][2] += a.w * b4.z; acc[3][3] += a.w * b4.w;
        }
        __syncthreads();
    }
#pragma unroll
    for (int i = 0; i < 4; i++) {
        float4 v = make_float4(acc[i][0], acc[i][1], acc[i][2], acc[i][3]);
        store4(&qprime[((size_t)(b * NHH + h) * SS + m0 + ty * 4 + i) * 576 + n0 + tx * 4], v);
    }
}

// ---------------------------------------------------------------------------
// MFMA flash attention (absorbed MLA).  Block = (b, h, 64 q-rows), 4 waves.
// Wave w: scores m-tile rows [s0+16w, +16); PV c-slice [128w, +128) as O^T.
// ---------------------------------------------------------------------------
#define KPAD 584   // ushorts per Kt row (576+8 -> bank-spread)
#define PPAD 40    // ushorts per Pt row (32+8)
#define SCL  0.10411760f  // (1/sqrt(192)) * log2(e)

__launch_bounds__(256, 2)
__global__ void attn_mfma(const ushort* __restrict__ qprime, const ushort* __restrict__ kvbf,
                          const ushort* __restrict__ kvT, const float* __restrict__ wkv_b,
                          const int* __restrict__ mask, ushort* __restrict__ o_heads)
{
    __shared__ char smem[43008];
    ushort* Kt = (ushort*)smem;                 // [32][KPAD]  37,376 B
    ushort* Pt = (ushort*)(smem + 37376);       // [64][PPAD]   5,120 B
    float* alpha_sh = (float*)(smem + 42496);   // [64]
    float* linv_sh  = (float*)(smem + 42752);   // [64]

    const int tid = threadIdx.x, w = tid >> 6, lane = tid & 63;
    const int l15 = lane & 15, q = lane >> 4;

    int j = blockIdx.x & 31, bh = blockIdx.x >> 5;
    int tile = (j & 1) ? (31 - (j >> 1)) : (j >> 1);   // big/small pairing
    int b = bh >> 4, h = bh & 15;
    int s0 = tile * 64;

    // Q A-frags for my m-tile (rows s0+16w .. +15), 18 k-chunks of 32
    bf16x8 qf[18];
    {
        const ushort* qbase = qprime + ((size_t)(b * NHH + h) * SS + (s0 + 16 * w + l15)) * 576 + q * 8;
#pragma unroll
        for (int k = 0; k < 18; k++) qf[k] = *(const bf16x8*)(qbase + k * 32);
    }

    f32x4 Oacc[8][4];
#pragma unroll
    for (int mt = 0; mt < 8; mt++)
#pragma unroll
        for (int nt = 0; nt < 4; nt++) Oacc[mt][nt] = (f32x4){0.f, 0.f, 0.f, 0.f};
    float m_i[4] = {-3e38f, -3e38f, -3e38f, -3e38f};
    float l_i[4] = {0.f, 0.f, 0.f, 0.f};

    const ushort* kvrow = kvbf + (size_t)b * SS * 576;
    const ushort* kvTb  = kvT + (size_t)b * 512 * SS;
    const int* mrow = mask + b * SS;
    const int nsteps = (s0 >> 5) + 2;

    for (int st = 0; st < nsteps; st++) {
        const int t0 = st * 32;
        // ---- stage K-tile (32 x 576 bf16) ----
#pragma unroll
        for (int i = 0; i < 9; i++) {
            int c = tid + 256 * i;
            int r = c / 72, o = c % 72;
            *(int4*)(Kt + r * KPAD + o * 8) = *(const int4*)(kvrow + (size_t)(t0 + r) * 576 + o * 8);
        }
        __syncthreads();
        // ---- scores: S(16 x 32) for my m-tile ----
        f32x4 sa0 = {0.f,0.f,0.f,0.f}, sa1 = {0.f,0.f,0.f,0.f};
        {
            const ushort* k0p = Kt + l15 * KPAD + q * 8;
            const ushort* k1p = Kt + (16 + l15) * KPAD + q * 8;
#pragma unroll
            for (int k = 0; k < 18; k++) {
                bf16x8 b0 = *(const bf16x8*)(k0p + k * 32);
                bf16x8 b1 = *(const bf16x8*)(k1p + k * 32);
                sa0 = __builtin_amdgcn_mfma_f32_16x16x32_bf16(qf[k], b0, sa0, 0, 0, 0);
                sa1 = __builtin_amdgcn_mfma_f32_16x16x32_bf16(qf[k], b1, sa1, 0, 0, 0);
            }
        }
        // ---- softmax (online) ----
        const int mv0 = mrow[t0 + l15];
        const int mv1 = mrow[t0 + 16 + l15];
        const bool edge = (t0 + 31 > s0 + 16 * w);
        float sc0[4], sc1[4];
#pragma unroll
        for (int r = 0; r < 4; r++) {
            sc0[r] = sa0[r] * SCL; sc1[r] = sa1[r] * SCL;
            int srow = s0 + 16 * w + 4 * q + r;
            if (edge) {
                if (t0 + l15 > srow || mv0 == 0) sc0[r] = -1e30f;
                if (t0 + 16 + l15 > srow || mv1 == 0) sc1[r] = -1e30f;
            } else {
                if (mv0 == 0) sc0[r] = -1e30f;
                if (mv1 == 0) sc1[r] = -1e30f;
            }
        }
        float alpha[4];
#pragma unroll
        for (int r = 0; r < 4; r++) {
            float mx = fmaxf(sc0[r], sc1[r]);
            mx = fmaxf(mx, __shfl_xor(mx, 1)); mx = fmaxf(mx, __shfl_xor(mx, 2));
            mx = fmaxf(mx, __shfl_xor(mx, 4)); mx = fmaxf(mx, __shfl_xor(mx, 8));
            float mn = fmaxf(m_i[r], mx);
            alpha[r] = exp2f(m_i[r] - mn);
            m_i[r] = mn;
            float p0 = (sc0[r] <= -1e29f) ? 0.f : exp2f(sc0[r] - mn);
            float p1 = (sc1[r] <= -1e29f) ? 0.f : exp2f(sc1[r] - mn);
            float rs = p0 + p1;
            rs += __shfl_xor(rs, 1); rs += __shfl_xor(rs, 2);
            rs += __shfl_xor(rs, 4); rs += __shfl_xor(rs, 8);
            l_i[r] = l_i[r] * alpha[r] + rs;
            int prow = 16 * w + 4 * q + r;
            Pt[prow * PPAD + l15]      = f2bf(p0);
            Pt[prow * PPAD + 16 + l15] = f2bf(p1);
        }
        if (l15 == 0) {
#pragma unroll
            for (int r = 0; r < 4; r++) alpha_sh[16 * w + 4 * q + r] = alpha[r];
        }
        __syncthreads();
        // ---- PV:  O^T(c-slice x 64s) += V^T-frag(global kvT) @ P^T(LDS) ----
        float av[4];
#pragma unroll
        for (int nt = 0; nt < 4; nt++) av[nt] = alpha_sh[16 * nt + l15];
#pragma unroll
        for (int mt = 0; mt < 8; mt++)
#pragma unroll
            for (int nt = 0; nt < 4; nt++) {
                Oacc[mt][nt][0] *= av[nt]; Oacc[mt][nt][1] *= av[nt];
                Oacc[mt][nt][2] *= av[nt]; Oacc[mt][nt][3] *= av[nt];
            }
        bf16x8 pb[4];
#pragma unroll
        for (int nt = 0; nt < 4; nt++)
            pb[nt] = *(const bf16x8*)(Pt + (16 * nt + l15) * PPAD + q * 8);
#pragma unroll
        for (int mt = 0; mt < 8; mt++) {
            bf16x8 af = *(const bf16x8*)(kvTb + (size_t)(128 * w + 16 * mt + l15) * SS + t0 + q * 8);
#pragma unroll
            for (int nt = 0; nt < 4; nt++)
                Oacc[mt][nt] = __builtin_amdgcn_mfma_f32_16x16x32_bf16(af, pb[nt], Oacc[mt][nt], 0, 0, 0);
        }
        __syncthreads();
    }

    // ---- epilogue: 1/l, W_UV projection, write o_heads ----
    if (l15 == 0) {
#pragma unroll
        for (int r = 0; r < 4; r++)
            linv_sh[16 * w + 4 * q + r] = (l_i[r] > 0.f) ? 1.f / l_i[r] : 0.f;
    }
    __syncthreads();
    float lv[4];
#pragma unroll
    for (int nt = 0; nt < 4; nt++) lv[nt] = linv_sh[16 * nt + l15];

    ushort* Oh = (ushort*)smem;   // [32][520]  33,280 B (reuses Kt/Pt space)
    for (int half = 0; half < 2; half++) {
        // write my O^T slice for this half's 32 rows, normalized, as [s][c] bf16
#pragma unroll
        for (int mt = 0; mt < 8; mt++)
#pragma unroll
            for (int i = 0; i < 2; i++) {
                int nt = 2 * half + i;
                f32x4 v = Oacc[mt][nt];
                ushort4 pk;
                pk.x = f2bf(v[0] * lv[nt]); pk.y = f2bf(v[1] * lv[nt]);
                pk.z = f2bf(v[2] * lv[nt]); pk.w = f2bf(v[3] * lv[nt]);
                *(ushort4*)(Oh + (size_t)(16 * i + l15) * 520 + 128 * w + 16 * mt + 4 * q) = pk;
            }
        __syncthreads();
        // F(32s x 32d for my d-slice) = O(32x512) @ WUV[d-slice]^T
        f32x4 fa[2][2];
        fa[0][0] = (f32x4){0,0,0,0}; fa[0][1] = (f32x4){0,0,0,0};
        fa[1][0] = (f32x4){0,0,0,0}; fa[1][1] = (f32x4){0,0,0,0};
        const float* wbase = wkv_b + ((size_t)(h * 256 + 128 + 32 * w + l15)) * 512 + q * 8;
#pragma unroll
        for (int k = 0; k < 16; k++) {
            bf16x8 a0 = *(const bf16x8*)(Oh + (size_t)l15 * 520 + k * 32 + q * 8);
            bf16x8 a1 = *(const bf16x8*)(Oh + (size_t)(16 + l15) * 520 + k * 32 + q * 8);
            const float* w0 = wbase + k * 32;
            const float* w1 = w0 + (size_t)16 * 512;
            float4 c0 = load4(w0), c1 = load4(w0 + 4);
            float4 d0 = load4(w1), d1 = load4(w1 + 4);
            bf16x8 b0, b1;
            b0[0]=(short)f2bf(c0.x); b0[1]=(short)f2bf(c0.y); b0[2]=(short)f2bf(c0.z); b0[3]=(short)f2bf(c0.w);
            b0[4]=(short)f2bf(c1.x); b0[5]=(short)f2bf(c1.y); b0[6]=(short)f2bf(c1.z); b0[7]=(short)f2bf(c1.w);
            b1[0]=(short)f2bf(d0.x); b1[1]=(short)f2bf(d0.y); b1[2]=(short)f2bf(d0.z); b1[3]=(short)f2bf(d0.w);
            b1[4]=(short)f2bf(d1.x); b1[5]=(short)f2bf(d1.y); b1[6]=(short)f2bf(d1.z); b1[7]=(short)f2bf(d1.w);
            fa[0][0] = __builtin_amdgcn_mfma_f32_16x16x32_bf16(a0, b0, fa[0][0], 0, 0, 0);
            fa[0][1] = __builtin_amdgcn_mfma_f32_16x16x32_bf16(a0, b1, fa[0][1], 0, 0, 0);
            fa[1][0] = __builtin_amdgcn_mfma_f32_16x16x32_bf16(a1, b0, fa[1][0], 0, 0, 0);
            fa[1][1] = __builtin_amdgcn_mfma_f32_16x16x32_bf16(a1, b1, fa[1][1], 0, 0, 0);
        }
        __syncthreads();
#pragma unroll
        for (int mts = 0; mts < 2; mts++)
#pragma unroll
            for (int ntd = 0; ntd < 2; ntd++)
#pragma unroll
                for (int r = 0; r < 4; r++) {
                    int s = s0 + 32 * half + 16 * mts + 4 * q + r;
                    int d = 32 * w + 16 * ntd + l15;
                    o_heads[(size_t)(b * SS + s) * 2048 + h * 128 + d] = f2bf(fa[mts][ntd][r]);
                }
    }
}

extern "C" void kernel_launch(void* const* d_in, const int* in_sizes, int n_in,
                              void* d_out, int out_size, void* d_ws, size_t ws_size,
                              hipStream_t stream)
{
    const float* x        = (const float*)d_in[0];
    const int*   mask     = (const int*)d_in[1];
    const float* wq_a_w   = (const float*)d_in[2];
    const float* wq_a_b   = (const float*)d_in[3];
    const float* q_norm_w = (const float*)d_in[4];
    const float* wq_b_w   = (const float*)d_in[5];
    const float* wq_b_b   = (const float*)d_in[6];
    const float* wkv_a_w  = (const float*)d_in[7];
    const float* wkv_a_b  = (const float*)d_in[8];
    const float* kv_norm_w= (const float*)d_in[9];
    const float* wkv_b_w  = (const float*)d_in[10];
    const float* wo_w     = (const float*)d_in[11];
    const float* wo_b     = (const float*)d_in[12];
    float* out = (float*)d_out;

    // ws layout (109,576,192 B total):
    //  [0, 25165824)        qbuf bf16 (4096x3072); later o_heads bf16 (4096x2048)
    //  [25165824, 29884416) kv_bf bf16 (4096x576)
    //  [29884416, 34078720) kvT bf16 (2x512x2048)
    //  [34078720, ...)      C region 75,497,472: q_a f32 / kvf f32 transient,
    //                       then qprime bf16 (2x16x2048x576)
    char* W = (char*)d_ws;
    ushort* qbuf    = (ushort*)W;
    ushort* o_heads = (ushort*)W;
    ushort* kvbf    = (ushort*)(W + 25165824);
    ushort* kvT     = (ushort*)(W + 29884416);
    char*   Cb      = W + 34078720;
    float*  q_a     = (float*)Cb;
    float*  kvf     = (float*)Cb;
    ushort* qprime  = (ushort*)Cb;

    // 1. q_a = x @ wq_a^T + b   (f32)
    gemm_nt<float, float><<<dim3(QLL / 64, MROWS / 64), 256, 0, stream>>>(
        x, wq_a_w, wq_a_b, q_a, MROWS, QLL, HH, HH, QLL);
    // 2. rms_norm(q_a)
    rmsnorm_kernel<<<MROWS, 256, 0, stream>>>(q_a, q_norm_w, QLL, QLL);
    // 3. q = q_a @ wq_b^T + b  -> qbuf bf16
    gemm_nt<float, ushort><<<dim3(NHH * QKH_D / 64, MROWS / 64), 256, 0, stream>>>(
        q_a, wq_b_w, wq_b_b, qbuf, MROWS, NHH * QKH_D, QLL, QLL, NHH * QKH_D);
    // 4. kv_full = x @ wkv_a^T + b  (f32, reuses q_a region)
    gemm_nt<float, float><<<dim3((KVLL + ROPE_D) / 64, MROWS / 64), 256, 0, stream>>>(
        x, wkv_a_w, wkv_a_b, kvf, MROWS, KVLL + ROPE_D, HH, HH, KVLL + ROPE_D);
    // 5. finalize kv: rms + rope -> kv_bf, kvT
    finalize_kv<<<MROWS, 256, 0, stream>>>(kvf, kv_norm_w, kvbf, kvT);
    // 6. rope q_pe -> qprime[512:576)  (clobbers kvf region; kvf dead)
    rope_q_kernel<<<dim3(MROWS, 4), 256, 0, stream>>>(qbuf, qprime);
    // 7. q_lat -> qprime[0:512)
    qlat_gemm<<<dim3(8, 32, 32), 256, 0, stream>>>(qbuf, wkv_b_w, qprime);
    // 8. MFMA flash attention -> o_heads bf16 (clobbers qbuf; dead)
    attn_mfma<<<BB * NHH * (SS / 64), 256, 0, stream>>>(
        qprime, kvbf, kvT, wkv_b_w, mask, o_heads);
    // 9. out = o_heads @ wo^T + b
    gemm_nt<ushort, float><<<dim3(HH / 64, MROWS / 64), 256, 0, stream>>>(
        o_heads, wo_w, wo_b, out, MROWS, HH, NHH * VD_D, NHH * VD_D, HH);
}

// Round 4
// 830.039 us; speedup vs baseline: 14.2074x; 4.6612x over previous
//
#include <hip/hip_runtime.h>
#include <hip/hip_bf16.h>

#define BB   2
#define SS   2048
#define HH   2048
#define NHH  16
#define QLL  1536
#define KVLL 512
#define NOPE_D 128
#define ROPE_D 64
#define QKH_D  192
#define VD_D   128
#define MROWS  (BB*SS)           // 4096 token rows

typedef __attribute__((ext_vector_type(8))) short bf16x8;   // 8 bf16 (4 VGPRs)
typedef __attribute__((ext_vector_type(4))) float f32x4;    // MFMA accumulator

__device__ inline float bf2f(unsigned short u) {
    union { float f; unsigned int i; } v; v.i = ((unsigned int)u) << 16; return v.f;
}
__device__ inline unsigned short f2bf(float f) {
    union { float f; unsigned int u; } v; v.f = f;
    unsigned int r = v.u + 0x7fffu + ((v.u >> 16) & 1u);
    return (unsigned short)(r >> 16);
}

// read 8 source elements -> bf16x8 (convert f32 on the fly)
__device__ inline bf16x8 ld8bf(const float* p) {
    float4 a = *(const float4*)p, b = *(const float4*)(p + 4);
    bf16x8 r;
    r[0]=(short)f2bf(a.x); r[1]=(short)f2bf(a.y); r[2]=(short)f2bf(a.z); r[3]=(short)f2bf(a.w);
    r[4]=(short)f2bf(b.x); r[5]=(short)f2bf(b.y); r[6]=(short)f2bf(b.z); r[7]=(short)f2bf(b.w);
    return r;
}
__device__ inline bf16x8 ld8bf(const ushort* p) { return *(const bf16x8*)p; }

// ---------------------------------------------------------------------------
// MFMA NT GEMM: C[m,n] = sum_k A[m,k]*B[n,k] (+bias[n]).  128x128 tile, BK=32,
// 256 threads (4 waves, each 64x64 = 4x4 frags of 16x16x32).  A/B converted
// to bf16 during LDS staging.  N guarded (rows clamped, stores skipped).
// z-batching: A += (z>>4)*Ab + (z&15)*Ah, likewise B, C.
// LDS chunk-XOR swizzle: chunk cq (2 bits) stored at cq ^ (row&3).
// ---------------------------------------------------------------------------
template<typename TA, typename TB, typename TC>
__launch_bounds__(256, 2)
__global__ void mfma_nt(const TA* __restrict__ A, int lda, size_t Ab, size_t Ah,
                        const TB* __restrict__ B, int ldb, size_t Bb, size_t Bh,
                        const float* __restrict__ bias,
                        TC* __restrict__ C, int ldc, size_t Cb, size_t Ch,
                        int M, int N, int K)
{
    __shared__ ushort As[128 * 32];
    __shared__ ushort Bs[128 * 32];
    const int z = blockIdx.z, bz = z >> 4, hz = z & 15;
    A += (size_t)bz * Ab + (size_t)hz * Ah;
    B += (size_t)bz * Bb + (size_t)hz * Bh;
    C += (size_t)bz * Cb + (size_t)hz * Ch;
    const int m0 = blockIdx.y * 128, n0 = blockIdx.x * 128;
    const int tid = threadIdx.x, w = tid >> 6, lane = tid & 63;
    const int l15 = lane & 15, q = lane >> 4;

    f32x4 acc[4][4];
#pragma unroll
    for (int i = 0; i < 4; i++)
#pragma unroll
        for (int j = 0; j < 4; j++) acc[i][j] = (f32x4){0.f, 0.f, 0.f, 0.f};

    const int mrow = 64 * (w & 1) + l15;   // + 16*mt
    const int nrow = 64 * (w >> 1) + l15;  // + 16*nt

    for (int k0 = 0; k0 < K; k0 += 32) {
#pragma unroll
        for (int p = 0; p < 2; p++) {
            int g = tid + (p << 8);
            int r = g >> 2, cq = g & 3;
            bf16x8 av = ld8bf(A + (size_t)(m0 + r) * lda + k0 + cq * 8);
            *(bf16x8*)(As + r * 32 + (((cq ^ r) & 3) << 3)) = av;
            int rb = n0 + r; if (rb > N - 1) rb = N - 1;
            bf16x8 bv = ld8bf(B + (size_t)rb * ldb + k0 + cq * 8);
            *(bf16x8*)(Bs + r * 32 + (((cq ^ r) & 3) << 3)) = bv;
        }
        __syncthreads();
        bf16x8 af[4], bf[4];
#pragma unroll
        for (int mt = 0; mt < 4; mt++) {
            int rr = mrow + 16 * mt;
            af[mt] = *(const bf16x8*)(As + rr * 32 + (((q ^ rr) & 3) << 3));
        }
#pragma unroll
        for (int nt = 0; nt < 4; nt++) {
            int rr = nrow + 16 * nt;
            bf[nt] = *(const bf16x8*)(Bs + rr * 32 + (((q ^ rr) & 3) << 3));
        }
#pragma unroll
        for (int mt = 0; mt < 4; mt++)
#pragma unroll
            for (int nt = 0; nt < 4; nt++)
                acc[mt][nt] = __builtin_amdgcn_mfma_f32_16x16x32_bf16(af[mt], bf[nt], acc[mt][nt], 0, 0, 0);
        __syncthreads();
    }

#pragma unroll
    for (int nt = 0; nt < 4; nt++) {
        int n = n0 + nrow + 16 * nt;
        if (n >= N) continue;
        float bv = bias ? bias[n] : 0.f;
#pragma unroll
        for (int mt = 0; mt < 4; mt++) {
#pragma unroll
            for (int r = 0; r < 4; r++) {
                int m = m0 + 64 * (w & 1) + 16 * mt + 4 * q + r;
                float v = acc[mt][nt][r] + bv;
                if constexpr (sizeof(TC) == 2) C[(size_t)m * ldc + n] = f2bf(v);
                else                           C[(size_t)m * ldc + n] = v;
            }
        }
    }
}

// ---------------------------------------------------------------------------
// RMSNorm f32 in -> bf16 out (q path).  One 256-thread block per row.
// ---------------------------------------------------------------------------
__launch_bounds__(256)
__global__ void rmsnorm_bf(const float* __restrict__ x, const float* __restrict__ w,
                           ushort* __restrict__ o, int width)
{
    const float* xr = x + (size_t)blockIdx.x * width;
    ushort* orow = o + (size_t)blockIdx.x * width;
    float ss = 0.f;
    for (int i = threadIdx.x; i < width; i += 256) { float v = xr[i]; ss += v * v; }
    __shared__ float red[256];
    red[threadIdx.x] = ss; __syncthreads();
    for (int off = 128; off > 0; off >>= 1) {
        if (threadIdx.x < off) red[threadIdx.x] += red[threadIdx.x + off];
        __syncthreads();
    }
    float r = rsqrtf(red[0] / (float)width + 1e-6f);
    for (int i = threadIdx.x; i < width; i += 256)
        orow[i] = f2bf(w[i] * xr[i] * r);
}

__device__ inline float rope_val(float xj, float xo, int j, int s)
{
    int i = j & 31;
    float freq = powf(10000.f, -(float)i / 32.f);
    float a = (float)s * freq;
    float sn, cs; sincosf(a, &sn, &cs);
    float other = (j < 32) ? -xo : xo;
    return xj * cs + other * sn;
}

// ---------------------------------------------------------------------------
// kv finalize: rms_norm latent 512 + rope pe 64 -> kvbf (4096x576 bf16)
// ---------------------------------------------------------------------------
__launch_bounds__(256)
__global__ void finalize_kv(const float* __restrict__ kvf, const float* __restrict__ w,
                            ushort* __restrict__ kvbf)
{
    int m = blockIdx.x, s = m & (SS - 1);
    const float* xr = kvf + (size_t)m * 576;
    float ss = 0.f;
    for (int i = threadIdx.x; i < 512; i += 256) { float v = xr[i]; ss += v * v; }
    __shared__ float red[256];
    red[threadIdx.x] = ss; __syncthreads();
    for (int off = 128; off > 0; off >>= 1) {
        if (threadIdx.x < off) red[threadIdx.x] += red[threadIdx.x + off];
        __syncthreads();
    }
    float r = rsqrtf(red[0] / 512.f + 1e-6f);
    for (int i = threadIdx.x; i < 512; i += 256)
        kvbf[(size_t)m * 576 + i] = f2bf(w[i] * xr[i] * r);
    if (threadIdx.x < 64) {
        int j = threadIdx.x;
        float xj = xr[512 + j], xo = xr[512 + (j ^ 32)];
        kvbf[(size_t)m * 576 + 512 + j] = f2bf(rope_val(xj, xo, j, s));
    }
}

// RoPE q_pe in place on qbuf bf16.  grid (4096,4) x 256; wave owns one head.
__global__ void rope_q_kernel(ushort* __restrict__ qbuf)
{
    int m = blockIdx.x, s = m & (SS - 1);
    int w = threadIdx.x >> 6, j = threadIdx.x & 63;
    int h = blockIdx.y * 4 + w;
    ushort* p = qbuf + (size_t)m * 3072 + h * QKH_D + NOPE_D;
    float xj = bf2f(p[j]);
    float xo = bf2f(p[j ^ 32]);
    p[j] = f2bf(rope_val(xj, xo, j, s));
}

// copy k_pe cols into Kf[...][128..191] for all heads.  grid 4096 x 256.
__global__ void copy_kpe(const ushort* __restrict__ kvbf, ushort* __restrict__ Kf)
{
    int m = blockIdx.x, b = m >> 11, t = m & (SS - 1);
    int j = threadIdx.x & 63;
    ushort v = kvbf[(size_t)m * 576 + 512 + j];
    for (int h = threadIdx.x >> 6; h < NHH; h += 4)
        Kf[((size_t)(b * NHH + h) * SS + t) * QKH_D + NOPE_D + j] = v;
}

// ---------------------------------------------------------------------------
// MFMA flash attention, materialized per-head K/V.
// Block = (b,h,64 q-rows), 4 waves.  Wave w: score m-tile rows [s0+16w,+16);
// PV d-slice [32w,+32) as O^T = VT-frags (global) @ P^T (LDS).
// LDS swizzles give <=2-way bank windows.
// ---------------------------------------------------------------------------
#define SCL  0.10411760f  // (1/sqrt(192)) * log2(e)

__device__ inline int kt_idx(int row, int chunk) {            // ushort index
    return row * 192 + (((chunk & ~7) | ((chunk ^ row) & 7)) << 3);
}
__device__ inline int pt_idx(int row, int chunk) {            // chunk of 8 cols
    return row * 32 + (((chunk ^ (row >> 1)) & 3) << 3);
}

__launch_bounds__(256, 2)
__global__ void attn_mfma(const ushort* __restrict__ qbuf, const ushort* __restrict__ Kf,
                          const ushort* __restrict__ VT, const int* __restrict__ mask,
                          ushort* __restrict__ o_heads)
{
    __shared__ ushort Kt[32 * 192];     // 12,288 B
    __shared__ ushort Pt[64 * 32];      //  4,096 B
    __shared__ float alpha_sh[64];
    __shared__ float linv_sh[64];

    const int tid = threadIdx.x, w = tid >> 6, lane = tid & 63;
    const int l15 = lane & 15, q = lane >> 4;

    int j = blockIdx.x & 31, bh = blockIdx.x >> 5;
    int tile = (j & 1) ? (31 - (j >> 1)) : (j >> 1);   // big/small pairing
    int b = bh >> 4, h = bh & 15;
    int s0 = tile * 64;

    // Q A-frags: rows s0+16w..+15, 6 k-chunks of 32 over the 192 dims
    bf16x8 qf[6];
    {
        const ushort* qbase = qbuf + ((size_t)(b * SS) + s0 + 16 * w + l15) * 3072 + h * QKH_D + q * 8;
#pragma unroll
        for (int k = 0; k < 6; k++) qf[k] = *(const bf16x8*)(qbase + k * 32);
    }

    f32x4 Oacc[2][4];
#pragma unroll
    for (int mt = 0; mt < 2; mt++)
#pragma unroll
        for (int nt = 0; nt < 4; nt++) Oacc[mt][nt] = (f32x4){0.f, 0.f, 0.f, 0.f};
    float m_i[4] = {-3e38f, -3e38f, -3e38f, -3e38f};
    float l_i[4] = {0.f, 0.f, 0.f, 0.f};

    const ushort* Kf_bh = Kf + (size_t)bh * SS * QKH_D;
    const ushort* VT_bh = VT + (size_t)bh * VD_D * SS;
    const int* mrow = mask + b * SS;
    const int nsteps = (s0 >> 5) + 2;

    for (int st = 0; st < nsteps; st++) {
        const int t0 = st * 32;
        // ---- stage K-tile (32 x 192 bf16), swizzled ----
#pragma unroll
        for (int i = 0; i < 3; i++) {
            int c = tid + (i << 8);                  // 768 chunks
            int r = c / 24, cc = c - r * 24;
            *(bf16x8*)(Kt + kt_idx(r, cc)) = *(const bf16x8*)(Kf_bh + (size_t)(t0 + r) * QKH_D + cc * 8);
        }
        __syncthreads();
        // ---- scores S(16x32) for my m-tile ----
        f32x4 sa0 = {0.f,0.f,0.f,0.f}, sa1 = {0.f,0.f,0.f,0.f};
#pragma unroll
        for (int k = 0; k < 6; k++) {
            bf16x8 b0 = *(const bf16x8*)(Kt + kt_idx(l15,      4 * k + q));
            bf16x8 b1 = *(const bf16x8*)(Kt + kt_idx(16 + l15, 4 * k + q));
            sa0 = __builtin_amdgcn_mfma_f32_16x16x32_bf16(qf[k], b0, sa0, 0, 0, 0);
            sa1 = __builtin_amdgcn_mfma_f32_16x16x32_bf16(qf[k], b1, sa1, 0, 0, 0);
        }
        // ---- online softmax ----
        const int mv0 = mrow[t0 + l15];
        const int mv1 = mrow[t0 + 16 + l15];
        const bool edge = (t0 + 31 > s0 + 16 * w);
        float sc0[4], sc1[4];
#pragma unroll
        for (int r = 0; r < 4; r++) {
            sc0[r] = sa0[r] * SCL; sc1[r] = sa1[r] * SCL;
            int srow = s0 + 16 * w + 4 * q + r;
            if (edge) {
                if (t0 + l15 > srow || mv0 == 0) sc0[r] = -1e30f;
                if (t0 + 16 + l15 > srow || mv1 == 0) sc1[r] = -1e30f;
            } else {
                if (mv0 == 0) sc0[r] = -1e30f;
                if (mv1 == 0) sc1[r] = -1e30f;
            }
        }
        float alpha[4];
#pragma unroll
        for (int r = 0; r < 4; r++) {
            float mx = fmaxf(sc0[r], sc1[r]);
            mx = fmaxf(mx, __shfl_xor(mx, 1)); mx = fmaxf(mx, __shfl_xor(mx, 2));
            mx = fmaxf(mx, __shfl_xor(mx, 4)); mx = fmaxf(mx, __shfl_xor(mx, 8));
            float mn = fmaxf(m_i[r], mx);
            alpha[r] = exp2f(m_i[r] - mn);
            m_i[r] = mn;
            float p0 = (sc0[r] <= -1e29f) ? 0.f : exp2f(sc0[r] - mn);
            float p1 = (sc1[r] <= -1e29f) ? 0.f : exp2f(sc1[r] - mn);
            float rs = p0 + p1;
            rs += __shfl_xor(rs, 1); rs += __shfl_xor(rs, 2);
            rs += __shfl_xor(rs, 4); rs += __shfl_xor(rs, 8);
            l_i[r] = l_i[r] * alpha[r] + rs;
            int prow = 16 * w + 4 * q + r;
            Pt[pt_idx(prow, l15 >> 3) + (l15 & 7)]      = f2bf(p0);
            Pt[pt_idx(prow, 2 + (l15 >> 3)) + (l15 & 7)] = f2bf(p1);
        }
        if (l15 == 0) {
#pragma unroll
            for (int r = 0; r < 4; r++) alpha_sh[16 * w + 4 * q + r] = alpha[r];
        }
        __syncthreads();
        // ---- PV: O^T d-slice [32w,+32) over 64 s ----
        float av[4];
#pragma unroll
        for (int nt = 0; nt < 4; nt++) av[nt] = alpha_sh[16 * nt + l15];
#pragma unroll
        for (int mt = 0; mt < 2; mt++)
#pragma unroll
            for (int nt = 0; nt < 4; nt++) {
                Oacc[mt][nt][0] *= av[nt]; Oacc[mt][nt][1] *= av[nt];
                Oacc[mt][nt][2] *= av[nt]; Oacc[mt][nt][3] *= av[nt];
            }
        bf16x8 pb[4];
#pragma unroll
        for (int nt = 0; nt < 4; nt++)
            pb[nt] = *(const bf16x8*)(Pt + pt_idx(16 * nt + l15, q));
#pragma unroll
        for (int mt = 0; mt < 2; mt++) {
            bf16x8 af = *(const bf16x8*)(VT_bh + (size_t)(32 * w + 16 * mt + l15) * SS + t0 + q * 8);
#pragma unroll
            for (int nt = 0; nt < 4; nt++)
                Oacc[mt][nt] = __builtin_amdgcn_mfma_f32_16x16x32_bf16(af, pb[nt], Oacc[mt][nt], 0, 0, 0);
        }
        __syncthreads();
    }

    // ---- epilogue: 1/l then write o_heads (O^T frags -> [s][d]) ----
    if (l15 == 0) {
#pragma unroll
        for (int r = 0; r < 4; r++)
            linv_sh[16 * w + 4 * q + r] = (l_i[r] > 0.f) ? 1.f / l_i[r] : 0.f;
    }
    __syncthreads();
#pragma unroll
    for (int mt = 0; mt < 2; mt++)
#pragma unroll
        for (int nt = 0; nt < 4; nt++) {
            float lv = linv_sh[16 * nt + l15];
            int s = s0 + 16 * nt + l15;
            int d = 32 * w + 16 * mt + 4 * q;
            ushort4 pk;
            pk.x = f2bf(Oacc[mt][nt][0] * lv); pk.y = f2bf(Oacc[mt][nt][1] * lv);
            pk.z = f2bf(Oacc[mt][nt][2] * lv); pk.w = f2bf(Oacc[mt][nt][3] * lv);
            *(ushort4*)(o_heads + (size_t)(b * SS + s) * 2048 + h * VD_D + d) = pk;
        }
}

extern "C" void kernel_launch(void* const* d_in, const int* in_sizes, int n_in,
                              void* d_out, int out_size, void* d_ws, size_t ws_size,
                              hipStream_t stream)
{
    const float* x        = (const float*)d_in[0];
    const int*   mask     = (const int*)d_in[1];
    const float* wq_a_w   = (const float*)d_in[2];
    const float* wq_a_b   = (const float*)d_in[3];
    const float* q_norm_w = (const float*)d_in[4];
    const float* wq_b_w   = (const float*)d_in[5];
    const float* wq_b_b   = (const float*)d_in[6];
    const float* wkv_a_w  = (const float*)d_in[7];
    const float* wkv_a_b  = (const float*)d_in[8];
    const float* kv_norm_w= (const float*)d_in[9];
    const float* wkv_b_w  = (const float*)d_in[10];
    const float* wo_w     = (const float*)d_in[11];
    const float* wo_b     = (const float*)d_in[12];
    float* out = (float*)d_out;

    // Workspace (98,041,856 B total; R3 proved >=109.5 MB available):
    // A [0,25165824):        q_a f32 (ph2-3)  -> Kf bf16 (2,16,2048,192) (ph7-10)
    // B [25165824,50331648): qbuf bf16 (4096x3072)          (ph4-10)
    // C [50331648,67108864): VT bf16 (2,16,128,2048)        (ph7-10)
    // D [67108864,83886080): q_a_bf (ph3-4) -> o_heads bf16 (ph10-11)
    // E [83886080,93323264): kvf f32 (4096x576)             (ph5-6)
    // F [93323264,98041856): kvbf bf16 (4096x576)           (ph6-10)
    char* W = (char*)d_ws;
    float*  q_a     = (float*)(W + 0);
    ushort* Kf      = (ushort*)(W + 0);
    ushort* qbuf    = (ushort*)(W + 25165824);
    ushort* VT      = (ushort*)(W + 50331648);
    ushort* q_a_bf  = (ushort*)(W + 67108864);
    ushort* o_heads = (ushort*)(W + 67108864);
    float*  kvf     = (float*)(W + 83886080);
    ushort* kvbf    = (ushort*)(W + 93323264);

    // 1. q_a = x @ wq_a^T + b        (f32 C)
    mfma_nt<float, float, float><<<dim3(QLL/128, MROWS/128, 1), 256, 0, stream>>>(
        x, HH, 0, 0, wq_a_w, HH, 0, 0, wq_a_b, q_a, QLL, 0, 0, MROWS, QLL, HH);
    // 2. rms_norm -> q_a_bf
    rmsnorm_bf<<<MROWS, 256, 0, stream>>>(q_a, q_norm_w, q_a_bf, QLL);
    // 3. q = q_a_bf @ wq_b^T + b -> qbuf bf16
    mfma_nt<ushort, float, ushort><<<dim3(3072/128, MROWS/128, 1), 256, 0, stream>>>(
        q_a_bf, QLL, 0, 0, wq_b_w, QLL, 0, 0, wq_b_b, qbuf, 3072, 0, 0, MROWS, 3072, QLL);
    // 4. kv_full = x @ wkv_a^T + b   (f32 C, N=576 guarded with 5 n-tiles)
    mfma_nt<float, float, float><<<dim3(5, MROWS/128, 1), 256, 0, stream>>>(
        x, HH, 0, 0, wkv_a_w, HH, 0, 0, wkv_a_b, kvf, 576, 0, 0, MROWS, 576, HH);
    // 5. finalize kv (rms + rope) -> kvbf
    finalize_kv<<<MROWS, 256, 0, stream>>>(kvf, kv_norm_w, kvbf);
    // 6. rope q_pe in place on qbuf
    rope_q_kernel<<<dim3(MROWS, 4), 256, 0, stream>>>(qbuf);
    // 7. Kf[b,h] = kv_lat @ W_UK[h]^T   (M=2048,N=128,K=512, z=32)
    mfma_nt<ushort, float, ushort><<<dim3(1, SS/128, 32), 256, 0, stream>>>(
        kvbf, 576, (size_t)SS * 576, 0,
        wkv_b_w, 512, 0, (size_t)256 * 512,
        nullptr, Kf, QKH_D, (size_t)NHH * SS * QKH_D, (size_t)SS * QKH_D,
        SS, NOPE_D, 512);
    // 8. k_pe broadcast into Kf cols 128..191
    copy_kpe<<<MROWS, 256, 0, stream>>>(kvbf, Kf);
    // 9. VT[b,h] = W_UV[h] @ kv_lat^T   (M=128,N=2048,K=512, z=32)
    mfma_nt<float, ushort, ushort><<<dim3(SS/128, 1, 32), 256, 0, stream>>>(
        wkv_b_w + (size_t)128 * 512, 512, 0, (size_t)256 * 512,
        kvbf, 576, (size_t)SS * 576, 0,
        nullptr, VT, SS, (size_t)NHH * VD_D * SS, (size_t)VD_D * SS,
        VD_D, SS, 512);
    // 10. MFMA flash attention -> o_heads bf16
    attn_mfma<<<BB * NHH * (SS / 64), 256, 0, stream>>>(qbuf, Kf, VT, mask, o_heads);
    // 11. out = o_heads @ wo^T + b
    mfma_nt<ushort, float, float><<<dim3(HH/128, MROWS/128, 1), 256, 0, stream>>>(
        o_heads, NHH * VD_D, 0, 0, wo_w, NHH * VD_D, 0, 0, wo_b, out, HH, 0, 0,
        MROWS, HH, NHH * VD_D);
}

// Round 5
// 569.873 us; speedup vs baseline: 20.6936x; 1.4565x over previous
//
#include <hip/hip_runtime.h>
#include <hip/hip_bf16.h>

#define BB   2
#define SS   2048
#define HH   2048
#define NHH  16
#define QLL  1536
#define KVLL 512
#define NOPE_D 128
#define ROPE_D 64
#define QKH_D  192
#define VD_D   128
#define MROWS  (BB*SS)           // 4096 token rows

typedef __attribute__((ext_vector_type(8))) short bf16x8;   // 8 bf16 (4 VGPRs)
typedef __attribute__((ext_vector_type(4))) float f32x4;    // MFMA accumulator

__device__ inline float bf2f(unsigned short u) {
    union { float f; unsigned int i; } v; v.i = ((unsigned int)u) << 16; return v.f;
}
__device__ inline unsigned short f2bf(float f) {
    union { float f; unsigned int u; } v; v.f = f;
    unsigned int r = v.u + 0x7fffu + ((v.u >> 16) & 1u);
    return (unsigned short)(r >> 16);
}

// ---------------------------------------------------------------------------
// f32 -> bf16 convert (grid-stride over 4-element groups)
// ---------------------------------------------------------------------------
__global__ void conv_bf(const float* __restrict__ in, ushort* __restrict__ out, int n4)
{
    int i = blockIdx.x * 256 + threadIdx.x;
    int stride = gridDim.x * 256;
    for (; i < n4; i += stride) {
        float4 v = ((const float4*)in)[i];
        ushort4 u;
        u.x = f2bf(v.x); u.y = f2bf(v.y); u.z = f2bf(v.z); u.w = f2bf(v.w);
        ((ushort4*)out)[i] = u;
    }
}

// ---------------------------------------------------------------------------
// All-bf16 MFMA NT GEMM: C[m,n] = sum_k A[m,k]*B[n,k] (+bias[n]).
// 128x128 tile, BK=64, 256 threads (4 waves, each 64x64 via 4x4 frags of
// 16x16x32).  M multiple of 128; N guarded (stage rows clamped, stores
// skipped); K multiple of 64.  z-batching: ptr += (z>>4)*Xb + (z&15)*Xh.
// LDS chunk-XOR swizzle (chunk ^ row) & 7 -> 2-way max on frag reads.
// ---------------------------------------------------------------------------
template<typename TC>
__launch_bounds__(256, 2)
__global__ void gemm_bf(const ushort* __restrict__ A, int lda, size_t Ab, size_t Ah,
                        const ushort* __restrict__ B, int ldb, size_t Bb, size_t Bh,
                        const float* __restrict__ bias,
                        TC* __restrict__ C, int ldc, size_t Cb, size_t Ch,
                        int M, int N, int K)
{
    __shared__ ushort As[128 * 64];
    __shared__ ushort Bs[128 * 64];
    const int z = blockIdx.z, bz = z >> 4, hz = z & 15;
    A += (size_t)bz * Ab + (size_t)hz * Ah;
    B += (size_t)bz * Bb + (size_t)hz * Bh;
    C += (size_t)bz * Cb + (size_t)hz * Ch;
    const int m0 = blockIdx.y * 128, n0 = blockIdx.x * 128;
    const int tid = threadIdx.x, w = tid >> 6, lane = tid & 63;
    const int l15 = lane & 15, q = lane >> 4;

    f32x4 acc[4][4];
#pragma unroll
    for (int i = 0; i < 4; i++)
#pragma unroll
        for (int j = 0; j < 4; j++) acc[i][j] = (f32x4){0.f, 0.f, 0.f, 0.f};

    const int mrow = 64 * (w & 1) + l15;   // + 16*mt
    const int nrow = 64 * (w >> 1) + l15;  // + 16*nt
    const int sr = tid >> 3, scq = tid & 7;   // staging row/chunk (128 rows x 8 chunks via 4 passes)

    for (int k0 = 0; k0 < K; k0 += 64) {
#pragma unroll
        for (int p = 0; p < 4; p++) {
            int r = sr + 32 * p;
            *(bf16x8*)(As + r * 64 + (((scq ^ r) & 7) << 3)) =
                *(const bf16x8*)(A + (size_t)(m0 + r) * lda + k0 + scq * 8);
            int rb = n0 + r; if (rb > N - 1) rb = N - 1;
            *(bf16x8*)(Bs + r * 64 + (((scq ^ r) & 7) << 3)) =
                *(const bf16x8*)(B + (size_t)rb * ldb + k0 + scq * 8);
        }
        __syncthreads();
#pragma unroll
        for (int ks = 0; ks < 2; ks++) {
            bf16x8 af[4], bf[4];
#pragma unroll
            for (int mt = 0; mt < 4; mt++) {
                int rr = mrow + 16 * mt;
                af[mt] = *(const bf16x8*)(As + rr * 64 + (((((ks << 2) + q) ^ rr) & 7) << 3));
            }
#pragma unroll
            for (int nt = 0; nt < 4; nt++) {
                int rr = nrow + 16 * nt;
                bf[nt] = *(const bf16x8*)(Bs + rr * 64 + (((((ks << 2) + q) ^ rr) & 7) << 3));
            }
#pragma unroll
            for (int mt = 0; mt < 4; mt++)
#pragma unroll
                for (int nt = 0; nt < 4; nt++)
                    acc[mt][nt] = __builtin_amdgcn_mfma_f32_16x16x32_bf16(af[mt], bf[nt], acc[mt][nt], 0, 0, 0);
        }
        __syncthreads();
    }

#pragma unroll
    for (int nt = 0; nt < 4; nt++) {
        int n = n0 + nrow + 16 * nt;
        if (n >= N) continue;
        float bv = bias ? bias[n] : 0.f;
#pragma unroll
        for (int mt = 0; mt < 4; mt++) {
#pragma unroll
            for (int r = 0; r < 4; r++) {
                int m = m0 + 64 * (w & 1) + 16 * mt + 4 * q + r;
                float v = acc[mt][nt][r] + bv;
                if constexpr (sizeof(TC) == 2) C[(size_t)m * ldc + n] = f2bf(v);
                else                           C[(size_t)m * ldc + n] = v;
            }
        }
    }
}

// ---------------------------------------------------------------------------
// RMSNorm f32 in -> bf16 out.  One 256-thread block per row.
// ---------------------------------------------------------------------------
__launch_bounds__(256)
__global__ void rmsnorm_bf(const float* __restrict__ x, const float* __restrict__ w,
                           ushort* __restrict__ o, int width)
{
    const float* xr = x + (size_t)blockIdx.x * width;
    ushort* orow = o + (size_t)blockIdx.x * width;
    float ss = 0.f;
    for (int i = threadIdx.x; i < width; i += 256) { float v = xr[i]; ss += v * v; }
    __shared__ float red[256];
    red[threadIdx.x] = ss; __syncthreads();
    for (int off = 128; off > 0; off >>= 1) {
        if (threadIdx.x < off) red[threadIdx.x] += red[threadIdx.x + off];
        __syncthreads();
    }
    float r = rsqrtf(red[0] / (float)width + 1e-6f);
    for (int i = threadIdx.x; i < width; i += 256)
        orow[i] = f2bf(w[i] * xr[i] * r);
}

__device__ inline float rope_val(float xj, float xo, int j, int s)
{
    int i = j & 31;
    float freq = powf(10000.f, -(float)i / 32.f);
    float a = (float)s * freq;
    float sn, cs; sincosf(a, &sn, &cs);
    float other = (j < 32) ? -xo : xo;
    return xj * cs + other * sn;
}

// kv finalize: rms_norm latent 512 + rope pe 64 -> kvbf (4096x576 bf16)
__launch_bounds__(256)
__global__ void finalize_kv(const float* __restrict__ kvf, const float* __restrict__ w,
                            ushort* __restrict__ kvbf)
{
    int m = blockIdx.x, s = m & (SS - 1);
    const float* xr = kvf + (size_t)m * 576;
    float ss = 0.f;
    for (int i = threadIdx.x; i < 512; i += 256) { float v = xr[i]; ss += v * v; }
    __shared__ float red[256];
    red[threadIdx.x] = ss; __syncthreads();
    for (int off = 128; off > 0; off >>= 1) {
        if (threadIdx.x < off) red[threadIdx.x] += red[threadIdx.x + off];
        __syncthreads();
    }
    float r = rsqrtf(red[0] / 512.f + 1e-6f);
    for (int i = threadIdx.x; i < 512; i += 256)
        kvbf[(size_t)m * 576 + i] = f2bf(w[i] * xr[i] * r);
    if (threadIdx.x < 64) {
        int j = threadIdx.x;
        float xj = xr[512 + j], xo = xr[512 + (j ^ 32)];
        kvbf[(size_t)m * 576 + 512 + j] = f2bf(rope_val(xj, xo, j, s));
    }
}

// RoPE q_pe in place on qbuf bf16.  grid (4096,4) x 256; wave owns one head.
__global__ void rope_q_kernel(ushort* __restrict__ qbuf)
{
    int m = blockIdx.x, s = m & (SS - 1);
    int w = threadIdx.x >> 6, j = threadIdx.x & 63;
    int h = blockIdx.y * 4 + w;
    ushort* p = qbuf + (size_t)m * 3072 + h * QKH_D + NOPE_D;
    float xj = bf2f(p[j]);
    float xo = bf2f(p[j ^ 32]);
    p[j] = f2bf(rope_val(xj, xo, j, s));
}

// copy k_pe cols into Kf[...][128..191] for all heads.  grid 4096 x 256.
__global__ void copy_kpe(const ushort* __restrict__ kvbf, ushort* __restrict__ Kf)
{
    int m = blockIdx.x, b = m >> 11, t = m & (SS - 1);
    int j = threadIdx.x & 63;
    ushort v = kvbf[(size_t)m * 576 + 512 + j];
    for (int h = threadIdx.x >> 6; h < NHH; h += 4)
        Kf[((size_t)(b * NHH + h) * SS + t) * QKH_D + NOPE_D + j] = v;
}

// ---------------------------------------------------------------------------
// MFMA flash attention, materialized per-head K/V, uniform-work pairing.
// Block = (b,h, tile-pair {j, 31-j}); each tile = 64 q-rows; 64-t steps.
// Total steps per block = (j+1) + (32-j) = 33 -> uniform across the grid.
// Wave w: scores for m-tile rows [s0+16w,+16); PV d-slice [32w,+32) as
// O^T = VT-frags (global) @ P-frags (LDS).
// ---------------------------------------------------------------------------
#define SCL  0.10411760f  // (1/sqrt(192)) * log2(e)
#define KTL  200          // Kt row length (192+8 pad -> 2-way banks)
#define PTL  72           // Pt row length (64+8 pad)

__launch_bounds__(256, 2)
__global__ void attn_mfma(const ushort* __restrict__ qbuf, const ushort* __restrict__ Kf,
                          const ushort* __restrict__ VT, const int* __restrict__ mask,
                          ushort* __restrict__ o_heads)
{
    __shared__ ushort Kt[64 * KTL];     // 25,600 B
    __shared__ ushort Pt[64 * PTL];     //  9,216 B
    __shared__ float alpha_sh[64];
    __shared__ float linv_sh[64];

    const int tid = threadIdx.x, w = tid >> 6, lane = tid & 63;
    const int l15 = lane & 15, q = lane >> 4;

    const int pr = blockIdx.x & 15, bh = blockIdx.x >> 4;
    const int b = bh >> 4, h = bh & 15;

    const ushort* Kf_bh = Kf + (size_t)bh * SS * QKH_D;
    const ushort* VT_bh = VT + (size_t)bh * VD_D * SS;
    const int* mrow = mask + b * SS;

    const int src = tid / 24 * 0;  (void)src;

    for (int ti = 0; ti < 2; ti++) {
        const int tile = ti ? (31 - pr) : pr;
        const int s0 = tile * 64;

        // Q A-frags: rows s0+16w..+15, 6 k-chunks of 32 over the 192 dims
        bf16x8 qf[6];
        {
            const ushort* qbase = qbuf + ((size_t)(b * SS) + s0 + 16 * w + l15) * 3072 + h * QKH_D + q * 8;
#pragma unroll
            for (int k = 0; k < 6; k++) qf[k] = *(const bf16x8*)(qbase + k * 32);
        }

        f32x4 Oacc[2][4];
#pragma unroll
        for (int mt = 0; mt < 2; mt++)
#pragma unroll
            for (int nt = 0; nt < 4; nt++) Oacc[mt][nt] = (f32x4){0.f, 0.f, 0.f, 0.f};
        float m_i[4] = {-3e38f, -3e38f, -3e38f, -3e38f};
        float l_i[4] = {0.f, 0.f, 0.f, 0.f};

        const int nsteps = tile + 1;
        for (int st = 0; st < nsteps; st++) {
            const int t0 = st * 64;
            // ---- stage K-tile (64 x 192 bf16) ----
#pragma unroll
            for (int i = 0; i < 6; i++) {
                int c = tid + (i << 8);                  // 1536 chunks
                int r = c / 24, cc = c - r * 24;
                *(bf16x8*)(Kt + r * KTL + cc * 8) =
                    *(const bf16x8*)(Kf_bh + (size_t)(t0 + r) * QKH_D + cc * 8);
            }
            __syncthreads();
            // ---- scores S(16 x 64) for my m-tile ----
            f32x4 sa[4];
#pragma unroll
            for (int c = 0; c < 4; c++) sa[c] = (f32x4){0.f, 0.f, 0.f, 0.f};
#pragma unroll
            for (int k = 0; k < 6; k++) {
#pragma unroll
                for (int c = 0; c < 4; c++) {
                    bf16x8 kb = *(const bf16x8*)(Kt + (16 * c + l15) * KTL + (4 * k + q) * 8);
                    sa[c] = __builtin_amdgcn_mfma_f32_16x16x32_bf16(qf[k], kb, sa[c], 0, 0, 0);
                }
            }
            // ---- online softmax over 64 cols ----
            int mv[4];
#pragma unroll
            for (int c = 0; c < 4; c++) mv[c] = mrow[t0 + 16 * c + l15];
            float alpha[4];
#pragma unroll
            for (int r = 0; r < 4; r++) {
                const int srow = s0 + 16 * w + 4 * q + r;
                float s_c[4];
#pragma unroll
                for (int c = 0; c < 4; c++) {
                    s_c[c] = sa[c][r] * SCL;
                    int col = t0 + 16 * c + l15;
                    if (col > srow || mv[c] == 0) s_c[c] = -1e30f;
                }
                float mx = fmaxf(fmaxf(s_c[0], s_c[1]), fmaxf(s_c[2], s_c[3]));
                mx = fmaxf(mx, __shfl_xor(mx, 1)); mx = fmaxf(mx, __shfl_xor(mx, 2));
                mx = fmaxf(mx, __shfl_xor(mx, 4)); mx = fmaxf(mx, __shfl_xor(mx, 8));
                float mn = fmaxf(m_i[r], mx);
                alpha[r] = exp2f(m_i[r] - mn);
                m_i[r] = mn;
                float ps = 0.f;
                const int prow = 16 * w + 4 * q + r;
#pragma unroll
                for (int c = 0; c < 4; c++) {
                    float pc = (s_c[c] <= -1e29f) ? 0.f : exp2f(s_c[c] - mn);
                    ps += pc;
                    Pt[prow * PTL + 16 * c + l15] = f2bf(pc);
                }
                ps += __shfl_xor(ps, 1); ps += __shfl_xor(ps, 2);
                ps += __shfl_xor(ps, 4); ps += __shfl_xor(ps, 8);
                l_i[r] = l_i[r] * alpha[r] + ps;
            }
            if (l15 == 0) {
#pragma unroll
                for (int r = 0; r < 4; r++) alpha_sh[16 * w + 4 * q + r] = alpha[r];
            }
            __syncthreads();
            // ---- PV: O^T d-slice [32w,+32) over 64 s, 64 t ----
            float av[4];
#pragma unroll
            for (int nt = 0; nt < 4; nt++) av[nt] = alpha_sh[16 * nt + l15];
#pragma unroll
            for (int mt = 0; mt < 2; mt++)
#pragma unroll
                for (int nt = 0; nt < 4; nt++) {
                    Oacc[mt][nt][0] *= av[nt]; Oacc[mt][nt][1] *= av[nt];
                    Oacc[mt][nt][2] *= av[nt]; Oacc[mt][nt][3] *= av[nt];
                }
            bf16x8 pb[4][2];
#pragma unroll
            for (int nt = 0; nt < 4; nt++)
#pragma unroll
                for (int kt = 0; kt < 2; kt++)
                    pb[nt][kt] = *(const bf16x8*)(Pt + (16 * nt + l15) * PTL + kt * 32 + q * 8);
#pragma unroll
            for (int mt = 0; mt < 2; mt++) {
#pragma unroll
                for (int kt = 0; kt < 2; kt++) {
                    bf16x8 af = *(const bf16x8*)(VT_bh + (size_t)(32 * w + 16 * mt + l15) * SS + t0 + kt * 32 + q * 8);
#pragma unroll
                    for (int nt = 0; nt < 4; nt++)
                        Oacc[mt][nt] = __builtin_amdgcn_mfma_f32_16x16x32_bf16(af, pb[nt][kt], Oacc[mt][nt], 0, 0, 0);
                }
            }
            __syncthreads();
        }

        // ---- tile epilogue: 1/l then write o_heads ----
        if (l15 == 0) {
#pragma unroll
            for (int r = 0; r < 4; r++)
                linv_sh[16 * w + 4 * q + r] = (l_i[r] > 0.f) ? 1.f / l_i[r] : 0.f;
        }
        __syncthreads();
#pragma unroll
        for (int mt = 0; mt < 2; mt++)
#pragma unroll
            for (int nt = 0; nt < 4; nt++) {
                float lv = linv_sh[16 * nt + l15];
                int s = s0 + 16 * nt + l15;
                int d = 32 * w + 16 * mt + 4 * q;
                ushort4 pk;
                pk.x = f2bf(Oacc[mt][nt][0] * lv); pk.y = f2bf(Oacc[mt][nt][1] * lv);
                pk.z = f2bf(Oacc[mt][nt][2] * lv); pk.w = f2bf(Oacc[mt][nt][3] * lv);
                *(ushort4*)(o_heads + (size_t)(b * SS + s) * 2048 + h * VD_D + d) = pk;
            }
        __syncthreads();
    }
}

extern "C" void kernel_launch(void* const* d_in, const int* in_sizes, int n_in,
                              void* d_out, int out_size, void* d_ws, size_t ws_size,
                              hipStream_t stream)
{
    const float* x        = (const float*)d_in[0];
    const int*   mask     = (const int*)d_in[1];
    const float* wq_a_w   = (const float*)d_in[2];
    const float* wq_a_b   = (const float*)d_in[3];
    const float* q_norm_w = (const float*)d_in[4];
    const float* wq_b_w   = (const float*)d_in[5];
    const float* wq_b_b   = (const float*)d_in[6];
    const float* wkv_a_w  = (const float*)d_in[7];
    const float* wkv_a_b  = (const float*)d_in[8];
    const float* kv_norm_w= (const float*)d_in[9];
    const float* wkv_b_w  = (const float*)d_in[10];
    const float* wo_w     = (const float*)d_in[11];
    const float* wo_b     = (const float*)d_in[12];
    float* out = (float*)d_out;

    // Workspace layout (108,527,616 B; R3 proved >=109,576,192 available):
    //  A [0,25165824):          wq_a_bf (ph0-1) -> qbuf bf16 (ph3-10)
    //  B [25165824,50331648):   q_a f32 (ph1-2) -> Kf bf16 (ph7-10)
    //  C [50331648,67108864):   x_bf (ph0-4)    -> VT bf16 (ph9-10)
    //  D [67108864,83886080):   q_a_bf (ph2-3) / kvf f32 (ph4-5) / o_heads (ph10-11)
    //  E [83886080,93323264):   wq_b_bf (ph0-3) -> kvbf (ph5-10)
    //  F [93323264,97517568):   wkv_b_bf (ph0-9)
    //  G [97517568,105906176):  wo_bf (ph0-11)
    //  H [105906176,108527616): wkv_a_bf padded to 640 rows (ph0-4)
    char* W = (char*)d_ws;
    ushort* wq_a_bf = (ushort*)(W + 0);
    ushort* qbuf    = (ushort*)(W + 0);
    float*  q_a     = (float*)(W + 25165824);
    ushort* Kf      = (ushort*)(W + 25165824);
    ushort* x_bf    = (ushort*)(W + 50331648);
    ushort* VT      = (ushort*)(W + 50331648);
    ushort* q_a_bf  = (ushort*)(W + 67108864);
    float*  kvf     = (float*)(W + 67108864);
    ushort* o_heads = (ushort*)(W + 67108864);
    ushort* wq_b_bf = (ushort*)(W + 83886080);
    ushort* kvbf    = (ushort*)(W + 83886080);
    ushort* wkv_b_bf= (ushort*)(W + 93323264);
    ushort* wo_bf   = (ushort*)(W + 97517568);
    ushort* wkv_a_bf= (ushort*)(W + 105906176);

    // 0. converts to bf16
    conv_bf<<<2048, 256, 0, stream>>>(x, x_bf, MROWS * HH / 4);
    conv_bf<<<2048, 256, 0, stream>>>(wq_a_w, wq_a_bf, QLL * HH / 4);
    conv_bf<<<2048, 256, 0, stream>>>(wq_b_w, wq_b_bf, 3072 * QLL / 4);
    conv_bf<<<1024, 256, 0, stream>>>(wkv_a_w, wkv_a_bf, 576 * HH / 4);
    conv_bf<<<1024, 256, 0, stream>>>(wkv_b_w, wkv_b_bf, NHH * 256 * 512 / 4);
    conv_bf<<<2048, 256, 0, stream>>>(wo_w, wo_bf, HH * 2048 / 4);

    // 1. q_a = x @ wq_a^T + b        (f32 C)
    gemm_bf<float><<<dim3(QLL/128, MROWS/128, 1), 256, 0, stream>>>(
        x_bf, HH, 0, 0, wq_a_bf, HH, 0, 0, wq_a_b, q_a, QLL, 0, 0, MROWS, QLL, HH);
    // 2. rms_norm -> q_a_bf
    rmsnorm_bf<<<MROWS, 256, 0, stream>>>(q_a, q_norm_w, q_a_bf, QLL);
    // 3. q = q_a_bf @ wq_b^T + b -> qbuf bf16
    gemm_bf<ushort><<<dim3(3072/128, MROWS/128, 1), 256, 0, stream>>>(
        q_a_bf, QLL, 0, 0, wq_b_bf, QLL, 0, 0, wq_b_b, qbuf, 3072, 0, 0, MROWS, 3072, QLL);
    // 4. kv_full = x @ wkv_a^T + b   (f32 C, N=576 guarded; weight padded to 640 rows)
    gemm_bf<float><<<dim3(5, MROWS/128, 1), 256, 0, stream>>>(
        x_bf, HH, 0, 0, wkv_a_bf, HH, 0, 0, wkv_a_b, kvf, 576, 0, 0, MROWS, 576, HH);
    // 5. finalize kv (rms + rope) -> kvbf
    finalize_kv<<<MROWS, 256, 0, stream>>>(kvf, kv_norm_w, kvbf);
    // 6. rope q_pe in place on qbuf
    rope_q_kernel<<<dim3(MROWS, 4), 256, 0, stream>>>(qbuf);
    // 7. Kf[b,h] = kv_lat @ W_UK[h]^T   (M=2048,N=128,K=512, z=32)
    gemm_bf<ushort><<<dim3(1, SS/128, 32), 256, 0, stream>>>(
        kvbf, 576, (size_t)SS * 576, 0,
        wkv_b_bf, 512, 0, (size_t)256 * 512,
        nullptr, Kf, QKH_D, (size_t)NHH * SS * QKH_D, (size_t)SS * QKH_D,
        SS, NOPE_D, 512);
    // 8. k_pe broadcast into Kf cols 128..191
    copy_kpe<<<MROWS, 256, 0, stream>>>(kvbf, Kf);
    // 9. VT[b,h] = W_UV[h] @ kv_lat^T   (M=128,N=2048,K=512, z=32)
    gemm_bf<ushort><<<dim3(SS/128, 1, 32), 256, 0, stream>>>(
        wkv_b_bf + (size_t)128 * 512, 512, 0, (size_t)256 * 512,
        kvbf, 576, (size_t)SS * 576, 0,
        nullptr, VT, SS, (size_t)NHH * VD_D * SS, (size_t)VD_D * SS,
        VD_D, SS, 512);
    // 10. MFMA flash attention -> o_heads bf16 (uniform pairs, grid 512)
    attn_mfma<<<BB * NHH * 16, 256, 0, stream>>>(qbuf, Kf, VT, mask, o_heads);
    // 11. out = o_heads @ wo^T + b
    gemm_bf<float><<<dim3(HH/128, MROWS/128, 1), 256, 0, stream>>>(
        o_heads, NHH * VD_D, 0, 0, wo_bf, NHH * VD_D, 0, 0, wo_b, out, HH, 0, 0,
        MROWS, HH, NHH * VD_D);
}